// Round 2
// baseline (14980.211 us; speedup 1.0000x reference)
//
#include <hip/hip_runtime.h>
#include <hip/hip_bf16.h>

#define NUM_USERS 100000
#define NUM_ITEMS 50000
#define N_NODES   150000
#define N_EDGES   4000000
#define H         64
#define BATCH     100000
#define MLP_HIDDEN 32

// ---------------------------------------------------------------------------
// 1. Degree histogram over dst (int atomics).
__global__ __launch_bounds__(256) void hist_kernel(const int* __restrict__ dst,
                                                   int* __restrict__ deg) {
    int e = blockIdx.x * 256 + threadIdx.x;
    if (e < N_EDGES) atomicAdd(&deg[dst[e]], 1);
}

// 2. Exclusive scan of deg -> offsets (+ cursor copy). Single 1024-thread block.
__global__ __launch_bounds__(1024) void scan_kernel(const int* __restrict__ deg,
                                                    int* __restrict__ offsets,
                                                    int* __restrict__ cursor) {
    __shared__ int part[1024];
    const int CH = (N_NODES + 1023) / 1024;   // 147
    int t = threadIdx.x;
    int start = t * CH;
    int end = min(start + CH, N_NODES);
    int s = 0;
    for (int i = start; i < end; ++i) s += deg[i];
    part[t] = s;
    __syncthreads();
    for (int off = 1; off < 1024; off <<= 1) {
        int v = (t >= off) ? part[t - off] : 0;
        __syncthreads();
        if (t >= off) part[t] += v;
        __syncthreads();
    }
    int base = (t == 0) ? 0 : part[t - 1];
    for (int i = start; i < end; ++i) {
        offsets[i] = base;
        cursor[i] = base;
        base += deg[i];
    }
}

// 3. Fill CSR: csr[cursor[dst]++] = src
__global__ __launch_bounds__(256) void fill_kernel(const int* __restrict__ src,
                                                   const int* __restrict__ dst,
                                                   int* __restrict__ cursor,
                                                   int* __restrict__ csr) {
    int e = blockIdx.x * 256 + threadIdx.x;
    if (e < N_EDGES) {
        int pos = atomicAdd(&cursor[dst[e]], 1);
        csr[pos] = src[e];
    }
}

// ---------------------------------------------------------------------------
// Fused SAGE layer: gather-mean over CSR neighbors + GEMM + relu.
// One 64-lane wave per node (lane = h dim); 4 nodes per 256-thread block.
__global__ __launch_bounds__(256) void sage_fused_kernel(const float* __restrict__ x,
                                                         float* __restrict__ y,
                                                         const int* __restrict__ offsets,
                                                         const int* __restrict__ deg,
                                                         const int* __restrict__ csr,
                                                         const float* __restrict__ Wl,
                                                         const float* __restrict__ bl,
                                                         const float* __restrict__ Wr) {
    __shared__ float sWl[H * H];
    __shared__ float sWr[H * H];
    __shared__ float sMean[4][H];
    __shared__ float sX[4][H];

    for (int i = threadIdx.x; i < H * H; i += 256) {
        sWl[i] = Wl[i];
        sWr[i] = Wr[i];
    }

    int slot = threadIdx.x >> 6;   // 0..3
    int h    = threadIdx.x & 63;   // 0..63
    int node = blockIdx.x * 4 + slot;   // N_NODES % 4 == 0

    int base = offsets[node];
    int cnt  = deg[node];

    float acc = 0.0f;
    for (int c = 0; c < cnt; c += 64) {
        int n = min(64, cnt - c);
        int eid = (c + h < cnt) ? csr[base + c + h] : 0;
        int i = 0;
        for (; i + 4 <= n; i += 4) {
            int s0 = __shfl(eid, i + 0, 64);
            int s1 = __shfl(eid, i + 1, 64);
            int s2 = __shfl(eid, i + 2, 64);
            int s3 = __shfl(eid, i + 3, 64);
            float v0 = x[(size_t)s0 * H + h];
            float v1 = x[(size_t)s1 * H + h];
            float v2 = x[(size_t)s2 * H + h];
            float v3 = x[(size_t)s3 * H + h];
            acc += (v0 + v1) + (v2 + v3);
        }
        for (; i < n; ++i) {
            int s0 = __shfl(eid, i, 64);
            acc += x[(size_t)s0 * H + h];
        }
    }
    float mean = acc / fmaxf((float)cnt, 1.0f);

    sMean[slot][h] = mean;
    sX[slot][h]    = x[(size_t)node * H + h];
    __syncthreads();

    float r = bl[h];
#pragma unroll
    for (int k = 0; k < H; ++k) {
        r = fmaf(sMean[slot][k], sWl[k * H + h], r);
        r = fmaf(sX[slot][k],    sWr[k * H + h], r);
    }
    y[(size_t)node * H + h] = fmaxf(r, 0.0f);
}

// ---------------------------------------------------------------------------
// Final MLP: rating = clip(relu(pair @ W1 + b1) @ W2 + b2, 1, 5)
__global__ __launch_bounds__(256) void mlp_kernel(const float* __restrict__ x,
                                                  const int* __restrict__ uids,
                                                  const int* __restrict__ iids,
                                                  const float* __restrict__ W1,
                                                  const float* __restrict__ b1,
                                                  const float* __restrict__ W2,
                                                  const float* __restrict__ b2,
                                                  float* __restrict__ out) {
    __shared__ float sW1[2 * H * MLP_HIDDEN];   // 128x32 = 16 KB
    __shared__ float sPair[8][2 * H];
    __shared__ float sW2[MLP_HIDDEN];

    for (int i = threadIdx.x; i < 2 * H * MLP_HIDDEN; i += 256) sW1[i] = W1[i];
    if (threadIdx.x < MLP_HIDDEN) sW2[threadIdx.x] = W2[threadIdx.x];

    int slot = threadIdx.x >> 5;   // 0..7
    int j    = threadIdx.x & 31;   // 0..31
    int b = blockIdx.x * 8 + slot; // BATCH % 8 == 0

    int u  = uids[b];
    int it = iids[b] + NUM_USERS;
    float2 a = *(const float2*)&x[(size_t)u * H + j * 2];
    sPair[slot][j * 2]     = a.x;
    sPair[slot][j * 2 + 1] = a.y;
    float2 c = *(const float2*)&x[(size_t)it * H + j * 2];
    sPair[slot][H + j * 2]     = c.x;
    sPair[slot][H + j * 2 + 1] = c.y;
    __syncthreads();

    float hacc = b1[j];
#pragma unroll
    for (int k = 0; k < 2 * H; ++k)
        hacc = fmaf(sPair[slot][k], sW1[k * MLP_HIDDEN + j], hacc);
    hacc = fmaxf(hacc, 0.0f);

    float r = hacc * sW2[j];
#pragma unroll
    for (int off = 16; off; off >>= 1) r += __shfl_down(r, off, 32);

    if (j == 0) out[b] = fminf(fmaxf(r + b2[0], 1.0f), 5.0f);
}

// ---------------------------------------------------------------------------
extern "C" void kernel_launch(void* const* d_in, const int* in_sizes, int n_in,
                              void* d_out, int out_size, void* d_ws, size_t ws_size,
                              hipStream_t stream) {
    const int*   edge_index = (const int*)d_in[0];   // [2, E]
    const int*   user_ids   = (const int*)d_in[1];
    const int*   item_ids   = (const int*)d_in[2];
    const float* user_emb   = (const float*)d_in[3];
    const float* item_emb   = (const float*)d_in[4];
    const float* Wl         = (const float*)d_in[5]; // [3,64,64]
    const float* bl         = (const float*)d_in[6]; // [3,64]
    const float* Wr         = (const float*)d_in[7]; // [3,64,64]
    const float* W1         = (const float*)d_in[8]; // [128,32]
    const float* b1         = (const float*)d_in[9];
    const float* W2         = (const float*)d_in[10];
    const float* b2         = (const float*)d_in[11];
    float* out = (float*)d_out;

    const int* src = edge_index;            // first row
    const int* dst = edge_index + N_EDGES;  // second row

    const size_t NH = (size_t)N_NODES * H;
    float* bufA    = (float*)d_ws;                 // 38.4 MB
    float* bufB    = bufA + NH;                    // 38.4 MB
    int*   deg     = (int*)(bufB + NH);            // 600 KB
    int*   offsets = deg + N_NODES;                // 600 KB (+1)
    int*   cursor  = offsets + N_NODES + 1;        // 600 KB
    int*   csr     = cursor + N_NODES;             // 16 MB

    // x = concat(user_emb, item_emb) -> bufA
    hipMemcpyAsync(bufA, user_emb, (size_t)NUM_USERS * H * sizeof(float),
                   hipMemcpyDeviceToDevice, stream);
    hipMemcpyAsync(bufA + (size_t)NUM_USERS * H, item_emb,
                   (size_t)NUM_ITEMS * H * sizeof(float),
                   hipMemcpyDeviceToDevice, stream);

    // CSR build (once per call; graph identical for all 3 layers)
    hipMemsetAsync(deg, 0, (size_t)N_NODES * sizeof(int), stream);
    hist_kernel<<<(N_EDGES + 255) / 256, 256, 0, stream>>>(dst, deg);
    scan_kernel<<<1, 1024, 0, stream>>>(deg, offsets, cursor);
    fill_kernel<<<(N_EDGES + 255) / 256, 256, 0, stream>>>(src, dst, cursor, csr);

    float* x = bufA;
    float* y = bufB;
    for (int l = 0; l < 3; ++l) {
        sage_fused_kernel<<<N_NODES / 4, 256, 0, stream>>>(
            x, y, offsets, deg, csr,
            Wl + (size_t)l * H * H, bl + (size_t)l * H, Wr + (size_t)l * H * H);
        float* t = x; x = y; y = t;
    }

    mlp_kernel<<<BATCH / 8, 256, 0, stream>>>(x, user_ids, item_ids, W1, b1, W2, b2, out);
}

// Round 3
// 1359.896 us; speedup vs baseline: 11.0157x; 11.0157x over previous
//
#include <hip/hip_runtime.h>
#include <hip/hip_bf16.h>

#define NUM_USERS 100000
#define NUM_ITEMS 50000
#define N_NODES   150000
#define N_EDGES   4000000
#define H         64
#define BATCH     100000
#define MLP_HIDDEN 32

// ---------------------------------------------------------------------------
// x = concat(user_emb, item_emb), float4-vectorized.
__global__ __launch_bounds__(256) void concat_kernel(const float* __restrict__ ue,
                                                     const float* __restrict__ ie,
                                                     float* __restrict__ x) {
    int i = blockIdx.x * 256 + threadIdx.x;        // float4 index
    const int UN4 = NUM_USERS * H / 4;             // 1.6M
    if (i < UN4) ((float4*)x)[i] = ((const float4*)ue)[i];
    else         ((float4*)x)[i] = ((const float4*)ie)[i - UN4];
}

// 1. Degree histogram over dst.
__global__ __launch_bounds__(256) void hist_kernel(const int* __restrict__ dst,
                                                   int* __restrict__ deg) {
    int e = blockIdx.x * 256 + threadIdx.x;
    if (e < N_EDGES) atomicAdd(&deg[dst[e]], 1);
}

// 2. Segment allocation: wave-scan of deg + one atomic bump per wave.
//    (Segment ORDER is arbitrary — gather only needs [offset, offset+deg).)
__global__ __launch_bounds__(256) void alloc_kernel(const int* __restrict__ deg,
                                                    int* __restrict__ offsets,
                                                    int* __restrict__ cursor,
                                                    int* __restrict__ counter) {
    int i = blockIdx.x * 256 + threadIdx.x;
    int lane = threadIdx.x & 63;
    int d = (i < N_NODES) ? deg[i] : 0;
    int v = d;                                    // inclusive wave scan
#pragma unroll
    for (int off = 1; off < 64; off <<= 1) {
        int t = __shfl_up(v, off, 64);
        if (lane >= off) v += t;
    }
    int total = __shfl(v, 63, 64);
    int base = 0;
    if (lane == 63) base = atomicAdd(counter, total);
    base = __shfl(base, 63, 64);
    if (i < N_NODES) {
        int o = base + v - d;                     // exclusive position
        offsets[i] = o;
        cursor[i]  = o;
    }
}

// 3. Fill CSR: csr[cursor[dst]++] = src
__global__ __launch_bounds__(256) void fill_kernel(const int* __restrict__ src,
                                                   const int* __restrict__ dst,
                                                   int* __restrict__ cursor,
                                                   int* __restrict__ csr) {
    int e = blockIdx.x * 256 + threadIdx.x;
    if (e < N_EDGES) {
        int pos = atomicAdd(&cursor[dst[e]], 1);
        csr[pos] = src[e];
    }
}

// ---------------------------------------------------------------------------
// Gather-mean: one wave per node, lane = feature. Lean: no LDS, deep unroll.
__global__ __launch_bounds__(256, 8) void gather_mean_kernel(const float* __restrict__ x,
                                                             float* __restrict__ mean,
                                                             const int* __restrict__ offsets,
                                                             const int* __restrict__ deg,
                                                             const int* __restrict__ csr) {
    int slot = threadIdx.x >> 6;
    int h    = threadIdx.x & 63;
    int node = blockIdx.x * 4 + slot;              // N_NODES % 4 == 0

    int base = offsets[node];
    int cnt  = deg[node];

    float acc = 0.0f;
    for (int c = 0; c < cnt; c += 64) {
        int n = min(64, cnt - c);
        int sid = (c + h < cnt) ? csr[base + c + h] : 0;
        int i = 0;
        for (; i + 8 <= n; i += 8) {
            int s0 = __shfl(sid, i + 0, 64);
            int s1 = __shfl(sid, i + 1, 64);
            int s2 = __shfl(sid, i + 2, 64);
            int s3 = __shfl(sid, i + 3, 64);
            int s4 = __shfl(sid, i + 4, 64);
            int s5 = __shfl(sid, i + 5, 64);
            int s6 = __shfl(sid, i + 6, 64);
            int s7 = __shfl(sid, i + 7, 64);
            float v0 = x[s0 * H + h];
            float v1 = x[s1 * H + h];
            float v2 = x[s2 * H + h];
            float v3 = x[s3 * H + h];
            float v4 = x[s4 * H + h];
            float v5 = x[s5 * H + h];
            float v6 = x[s6 * H + h];
            float v7 = x[s7 * H + h];
            acc += ((v0 + v1) + (v2 + v3)) + ((v4 + v5) + (v6 + v7));
        }
        for (; i < n; ++i) {
            int s0 = __shfl(sid, i, 64);
            acc += x[s0 * H + h];
        }
    }
    mean[node * H + h] = acc / fmaxf((float)cnt, 1.0f);
}

// ---------------------------------------------------------------------------
// Transform: x = relu(mean @ Wl + bl + x @ Wr), IN PLACE (each thread touches
// only its own node's row, read before write, barrier in between).
__global__ __launch_bounds__(512) void sage_transform_kernel(float* __restrict__ x,
                                                             const float* __restrict__ mean,
                                                             const float* __restrict__ Wl,
                                                             const float* __restrict__ bl,
                                                             const float* __restrict__ Wr) {
    __shared__ float sWl[H * H];
    __shared__ float sWr[H * H];
    __shared__ float sM[8][H];
    __shared__ float sX[8][H];

    for (int i = threadIdx.x; i < H * H; i += 512) {
        sWl[i] = Wl[i];
        sWr[i] = Wr[i];
    }

    int slot = threadIdx.x >> 6;                   // 0..7
    int h    = threadIdx.x & 63;
    int node = blockIdx.x * 8 + slot;              // N_NODES % 8 == 0

    sM[slot][h] = mean[node * H + h];
    sX[slot][h] = x[node * H + h];
    __syncthreads();

    float r = bl[h];
#pragma unroll
    for (int k = 0; k < H; ++k) {
        r = fmaf(sM[slot][k], sWl[k * H + h], r);
        r = fmaf(sX[slot][k], sWr[k * H + h], r);
    }
    x[node * H + h] = fmaxf(r, 0.0f);
}

// ---------------------------------------------------------------------------
// Final MLP: rating = clip(relu(pair @ W1 + b1) @ W2 + b2, 1, 5)
__global__ __launch_bounds__(256) void mlp_kernel(const float* __restrict__ x,
                                                  const int* __restrict__ uids,
                                                  const int* __restrict__ iids,
                                                  const float* __restrict__ W1,
                                                  const float* __restrict__ b1,
                                                  const float* __restrict__ W2,
                                                  const float* __restrict__ b2,
                                                  float* __restrict__ out) {
    __shared__ float sW1[2 * H * MLP_HIDDEN];
    __shared__ float sPair[8][2 * H];
    __shared__ float sW2[MLP_HIDDEN];

    for (int i = threadIdx.x; i < 2 * H * MLP_HIDDEN; i += 256) sW1[i] = W1[i];
    if (threadIdx.x < MLP_HIDDEN) sW2[threadIdx.x] = W2[threadIdx.x];

    int slot = threadIdx.x >> 5;
    int j    = threadIdx.x & 31;
    int b = blockIdx.x * 8 + slot;                 // BATCH % 8 == 0

    int u  = uids[b];
    int it = iids[b] + NUM_USERS;
    float2 a = *(const float2*)&x[u * H + j * 2];
    sPair[slot][j * 2]     = a.x;
    sPair[slot][j * 2 + 1] = a.y;
    float2 c = *(const float2*)&x[it * H + j * 2];
    sPair[slot][H + j * 2]     = c.x;
    sPair[slot][H + j * 2 + 1] = c.y;
    __syncthreads();

    float hacc = b1[j];
#pragma unroll
    for (int k = 0; k < 2 * H; ++k)
        hacc = fmaf(sPair[slot][k], sW1[k * MLP_HIDDEN + j], hacc);
    hacc = fmaxf(hacc, 0.0f);

    float r = hacc * sW2[j];
#pragma unroll
    for (int off = 16; off; off >>= 1) r += __shfl_down(r, off, 32);

    if (j == 0) out[b] = fminf(fmaxf(r + b2[0], 1.0f), 5.0f);
}

// ---------------------------------------------------------------------------
extern "C" void kernel_launch(void* const* d_in, const int* in_sizes, int n_in,
                              void* d_out, int out_size, void* d_ws, size_t ws_size,
                              hipStream_t stream) {
    const int*   edge_index = (const int*)d_in[0];
    const int*   user_ids   = (const int*)d_in[1];
    const int*   item_ids   = (const int*)d_in[2];
    const float* user_emb   = (const float*)d_in[3];
    const float* item_emb   = (const float*)d_in[4];
    const float* Wl         = (const float*)d_in[5];
    const float* bl         = (const float*)d_in[6];
    const float* Wr         = (const float*)d_in[7];
    const float* W1         = (const float*)d_in[8];
    const float* b1         = (const float*)d_in[9];
    const float* W2         = (const float*)d_in[10];
    const float* b2         = (const float*)d_in[11];
    float* out = (float*)d_out;

    const int* src = edge_index;
    const int* dst = edge_index + N_EDGES;

    const size_t NH = (size_t)N_NODES * H;
    float* x       = (float*)d_ws;                 // 38.4 MB
    float* mean    = x + NH;                       // 38.4 MB
    int*   deg     = (int*)(mean + NH);            // 600 KB
    int*   counter = deg + N_NODES;                // 4 B  (memset together with deg)
    int*   offsets = counter + 1;
    int*   cursor  = offsets + N_NODES;
    int*   csr     = cursor + N_NODES;             // 16 MB

    concat_kernel<<<(N_NODES * H / 4) / 256, 256, 0, stream>>>(user_emb, item_emb, x);

    // CSR build (graph identical across layers -> once per call)
    hipMemsetAsync(deg, 0, (size_t)(N_NODES + 1) * sizeof(int), stream);  // deg + counter
    hist_kernel<<<(N_EDGES + 255) / 256, 256, 0, stream>>>(dst, deg);
    alloc_kernel<<<(N_NODES + 255) / 256, 256, 0, stream>>>(deg, offsets, cursor, counter);
    fill_kernel<<<(N_EDGES + 255) / 256, 256, 0, stream>>>(src, dst, cursor, csr);

    for (int l = 0; l < 3; ++l) {
        gather_mean_kernel<<<N_NODES / 4, 256, 0, stream>>>(x, mean, offsets, deg, csr);
        sage_transform_kernel<<<N_NODES / 8, 512, 0, stream>>>(
            x, mean, Wl + (size_t)l * H * H, bl + (size_t)l * H, Wr + (size_t)l * H * H);
    }

    mlp_kernel<<<BATCH / 8, 256, 0, stream>>>(x, user_ids, item_ids, W1, b1, W2, b2, out);
}

// Round 4
// 959.667 us; speedup vs baseline: 15.6098x; 1.4170x over previous
//
#include <hip/hip_runtime.h>
#include <hip/hip_bf16.h>

#define NUM_USERS 100000
#define NUM_ITEMS 50000
#define N_NODES   150000
#define N_EDGES   4000000
#define H         64
#define BATCH     100000
#define MLP_HIDDEN 32
#define NBUCK     586          // ceil(N_NODES / 256); bucket = dst >> 8

// ---------------------------------------------------------------------------
// x = concat(user_emb, item_emb), float4-vectorized.
__global__ __launch_bounds__(256) void concat_kernel(const float* __restrict__ ue,
                                                     const float* __restrict__ ie,
                                                     float* __restrict__ x) {
    int i = blockIdx.x * 256 + threadIdx.x;        // float4 index
    const int UN4 = NUM_USERS * H / 4;
    if (i < UN4) ((float4*)x)[i] = ((const float4*)ue)[i];
    else         ((float4*)x)[i] = ((const float4*)ie)[i - UN4];
}

// ---------------------------------------------------------------------------
// CSR build, pass 1: per-bucket edge counts (LDS histogram per block).
__global__ __launch_bounds__(256) void bucket_hist_kernel(const int* __restrict__ dst,
                                                          int* __restrict__ bucketCnt) {
    __shared__ int histL[NBUCK];
    for (int i = threadIdx.x; i < NBUCK; i += 256) histL[i] = 0;
    __syncthreads();
    int stride = gridDim.x * 256;
    for (int e = blockIdx.x * 256 + threadIdx.x; e < N_EDGES; e += stride)
        atomicAdd(&histL[dst[e] >> 8], 1);
    __syncthreads();
    for (int i = threadIdx.x; i < NBUCK; i += 256)
        if (histL[i]) atomicAdd(&bucketCnt[i], histL[i]);
}

// CSR build, pass 2: exclusive scan of bucket counts (single wave).
__global__ __launch_bounds__(64) void bucket_scan_kernel(const int* __restrict__ bucketCnt,
                                                         int* __restrict__ bucketBase,
                                                         int* __restrict__ bucketCursor) {
    int t = threadIdx.x;                 // 0..63
    const int CH = (NBUCK + 63) / 64;    // 10
    int start = t * CH;
    int end = min(start + CH, NBUCK);
    int s = 0;
    for (int i = start; i < end; ++i) s += bucketCnt[i];
    int v = s;
#pragma unroll
    for (int off = 1; off < 64; off <<= 1) {
        int u = __shfl_up(v, off, 64);
        if (t >= off) v += u;
    }
    int base = v - s;                    // exclusive
    for (int i = start; i < end; ++i) {
        bucketBase[i] = base;
        bucketCursor[i] = base;
        base += bucketCnt[i];
    }
}

// CSR build, pass 3: scatter edges into bucket-contiguous ebuf.
// Entry packed as (src << 8) | (dst & 255): src < 2^18, dstLocal < 2^8.
#define SCHUNK 8192
__global__ __launch_bounds__(256) void bucket_scatter_kernel(const int* __restrict__ src,
                                                             const int* __restrict__ dst,
                                                             int* __restrict__ bucketCursor,
                                                             int* __restrict__ ebuf) {
    __shared__ int histL[NBUCK];
    __shared__ int curL[NBUCK];
    int base = blockIdx.x * SCHUNK;
    int end = min(base + SCHUNK, N_EDGES);
    for (int i = threadIdx.x; i < NBUCK; i += 256) histL[i] = 0;
    __syncthreads();
    for (int e = base + threadIdx.x; e < end; e += 256)
        atomicAdd(&histL[dst[e] >> 8], 1);
    __syncthreads();
    for (int b = threadIdx.x; b < NBUCK; b += 256)
        curL[b] = histL[b] ? atomicAdd(&bucketCursor[b], histL[b]) : 0;
    __syncthreads();
    for (int e = base + threadIdx.x; e < end; e += 256) {
        int d = dst[e];
        int pos = atomicAdd(&curL[d >> 8], 1);
        ebuf[pos] = (src[e] << 8) | (d & 255);
    }
}

// CSR build, pass 4: one block per bucket — local degrees, local scan, fill.
// Also emits global deg[] and offsets[].
__global__ __launch_bounds__(256) void bucket_build_kernel(const int* __restrict__ ebuf,
                                                           const int* __restrict__ bucketBase,
                                                           const int* __restrict__ bucketCnt,
                                                           int* __restrict__ deg,
                                                           int* __restrict__ offsets,
                                                           int* __restrict__ csr) {
    __shared__ int degL[256];
    __shared__ int scanL[256];
    __shared__ int curL[256];
    int t = threadIdx.x;
    int b = blockIdx.x;
    int nodeBase = b << 8;
    int start = bucketBase[b];
    int cnt = bucketCnt[b];

    degL[t] = 0;
    __syncthreads();
    for (int i = t; i < cnt; i += 256)
        atomicAdd(&degL[ebuf[start + i] & 255], 1);
    __syncthreads();

    int v = degL[t];
    scanL[t] = v;
    __syncthreads();
#pragma unroll
    for (int off = 1; off < 256; off <<= 1) {
        int u = (t >= off) ? scanL[t - off] : 0;
        __syncthreads();
        scanL[t] += u;
        __syncthreads();
    }
    int excl = scanL[t] - v;

    int node = nodeBase + t;
    if (node < N_NODES) {
        deg[node] = v;
        offsets[node] = start + excl;
    }
    curL[t] = excl;
    __syncthreads();

    for (int i = t; i < cnt; i += 256) {
        unsigned p = (unsigned)ebuf[start + i];
        int pos = atomicAdd(&curL[p & 255u], 1);
        csr[start + pos] = (int)(p >> 8);
    }
}

// ---------------------------------------------------------------------------
// Gather-mean: one wave per node, lane = feature.
__global__ __launch_bounds__(256, 8) void gather_mean_kernel(const float* __restrict__ x,
                                                             float* __restrict__ mean,
                                                             const int* __restrict__ offsets,
                                                             const int* __restrict__ deg,
                                                             const int* __restrict__ csr) {
    int slot = threadIdx.x >> 6;
    int h    = threadIdx.x & 63;
    int node = blockIdx.x * 4 + slot;              // N_NODES % 4 == 0

    int base = offsets[node];
    int cnt  = deg[node];

    float acc = 0.0f;
    for (int c = 0; c < cnt; c += 64) {
        int n = min(64, cnt - c);
        int sid = (c + h < cnt) ? csr[base + c + h] : 0;
        int i = 0;
        for (; i + 8 <= n; i += 8) {
            int s0 = __shfl(sid, i + 0, 64);
            int s1 = __shfl(sid, i + 1, 64);
            int s2 = __shfl(sid, i + 2, 64);
            int s3 = __shfl(sid, i + 3, 64);
            int s4 = __shfl(sid, i + 4, 64);
            int s5 = __shfl(sid, i + 5, 64);
            int s6 = __shfl(sid, i + 6, 64);
            int s7 = __shfl(sid, i + 7, 64);
            float v0 = x[s0 * H + h];
            float v1 = x[s1 * H + h];
            float v2 = x[s2 * H + h];
            float v3 = x[s3 * H + h];
            float v4 = x[s4 * H + h];
            float v5 = x[s5 * H + h];
            float v6 = x[s6 * H + h];
            float v7 = x[s7 * H + h];
            acc += ((v0 + v1) + (v2 + v3)) + ((v4 + v5) + (v6 + v7));
        }
        for (; i < n; ++i) {
            int s0 = __shfl(sid, i, 64);
            acc += x[s0 * H + h];
        }
    }
    mean[node * H + h] = acc / fmaxf((float)cnt, 1.0f);
}

// ---------------------------------------------------------------------------
// Transform: x = relu(mean @ Wl + bl + x @ Wr), IN PLACE.
__global__ __launch_bounds__(512) void sage_transform_kernel(float* __restrict__ x,
                                                             const float* __restrict__ mean,
                                                             const float* __restrict__ Wl,
                                                             const float* __restrict__ bl,
                                                             const float* __restrict__ Wr) {
    __shared__ float sWl[H * H];
    __shared__ float sWr[H * H];
    __shared__ float sM[8][H];
    __shared__ float sX[8][H];

    for (int i = threadIdx.x; i < H * H; i += 512) {
        sWl[i] = Wl[i];
        sWr[i] = Wr[i];
    }

    int slot = threadIdx.x >> 6;
    int h    = threadIdx.x & 63;
    int node = blockIdx.x * 8 + slot;              // N_NODES % 8 == 0

    sM[slot][h] = mean[node * H + h];
    sX[slot][h] = x[node * H + h];
    __syncthreads();

    float r = bl[h];
#pragma unroll
    for (int k = 0; k < H; ++k) {
        r = fmaf(sM[slot][k], sWl[k * H + h], r);
        r = fmaf(sX[slot][k], sWr[k * H + h], r);
    }
    x[node * H + h] = fmaxf(r, 0.0f);
}

// ---------------------------------------------------------------------------
// Final MLP: rating = clip(relu(pair @ W1 + b1) @ W2 + b2, 1, 5)
__global__ __launch_bounds__(256) void mlp_kernel(const float* __restrict__ x,
                                                  const int* __restrict__ uids,
                                                  const int* __restrict__ iids,
                                                  const float* __restrict__ W1,
                                                  const float* __restrict__ b1,
                                                  const float* __restrict__ W2,
                                                  const float* __restrict__ b2,
                                                  float* __restrict__ out) {
    __shared__ float sW1[2 * H * MLP_HIDDEN];
    __shared__ float sPair[8][2 * H];
    __shared__ float sW2[MLP_HIDDEN];

    for (int i = threadIdx.x; i < 2 * H * MLP_HIDDEN; i += 256) sW1[i] = W1[i];
    if (threadIdx.x < MLP_HIDDEN) sW2[threadIdx.x] = W2[threadIdx.x];

    int slot = threadIdx.x >> 5;
    int j    = threadIdx.x & 31;
    int b = blockIdx.x * 8 + slot;                 // BATCH % 8 == 0

    int u  = uids[b];
    int it = iids[b] + NUM_USERS;
    float2 a = *(const float2*)&x[u * H + j * 2];
    sPair[slot][j * 2]     = a.x;
    sPair[slot][j * 2 + 1] = a.y;
    float2 c = *(const float2*)&x[it * H + j * 2];
    sPair[slot][H + j * 2]     = c.x;
    sPair[slot][H + j * 2 + 1] = c.y;
    __syncthreads();

    float hacc = b1[j];
#pragma unroll
    for (int k = 0; k < 2 * H; ++k)
        hacc = fmaf(sPair[slot][k], sW1[k * MLP_HIDDEN + j], hacc);
    hacc = fmaxf(hacc, 0.0f);

    float r = hacc * sW2[j];
#pragma unroll
    for (int off = 16; off; off >>= 1) r += __shfl_down(r, off, 32);

    if (j == 0) out[b] = fminf(fmaxf(r + b2[0], 1.0f), 5.0f);
}

// ---------------------------------------------------------------------------
extern "C" void kernel_launch(void* const* d_in, const int* in_sizes, int n_in,
                              void* d_out, int out_size, void* d_ws, size_t ws_size,
                              hipStream_t stream) {
    const int*   edge_index = (const int*)d_in[0];
    const int*   user_ids   = (const int*)d_in[1];
    const int*   item_ids   = (const int*)d_in[2];
    const float* user_emb   = (const float*)d_in[3];
    const float* item_emb   = (const float*)d_in[4];
    const float* Wl         = (const float*)d_in[5];
    const float* bl         = (const float*)d_in[6];
    const float* Wr         = (const float*)d_in[7];
    const float* W1         = (const float*)d_in[8];
    const float* b1         = (const float*)d_in[9];
    const float* W2         = (const float*)d_in[10];
    const float* b2         = (const float*)d_in[11];
    float* out = (float*)d_out;

    const int* src = edge_index;
    const int* dst = edge_index + N_EDGES;

    const size_t NH = (size_t)N_NODES * H;
    float* x         = (float*)d_ws;               // 38.4 MB
    float* mean      = x + NH;                     // 38.4 MB
    int* deg         = (int*)(mean + NH);          // 600 KB
    int* offsets     = deg + N_NODES;              // 600 KB
    int* bucketCnt   = offsets + N_NODES;          // 2.3 KB
    int* bucketBase  = bucketCnt + NBUCK;
    int* bucketCursor= bucketBase + NBUCK;
    int* csr         = bucketCursor + NBUCK;       // 16 MB
    int* ebuf        = (int*)mean;                 // 16 MB, overlaid on mean
                                                   // (CSR build finishes before
                                                   //  the first gather writes mean)

    concat_kernel<<<(N_NODES * H / 4) / 256, 256, 0, stream>>>(user_emb, item_emb, x);

    // CSR build via two-level counting sort (graph identical across layers)
    hipMemsetAsync(bucketCnt, 0, NBUCK * sizeof(int), stream);
    bucket_hist_kernel<<<2048, 256, 0, stream>>>(dst, bucketCnt);
    bucket_scan_kernel<<<1, 64, 0, stream>>>(bucketCnt, bucketBase, bucketCursor);
    bucket_scatter_kernel<<<(N_EDGES + SCHUNK - 1) / SCHUNK, 256, 0, stream>>>(
        src, dst, bucketCursor, ebuf);
    bucket_build_kernel<<<NBUCK, 256, 0, stream>>>(ebuf, bucketBase, bucketCnt,
                                                   deg, offsets, csr);

    for (int l = 0; l < 3; ++l) {
        gather_mean_kernel<<<N_NODES / 4, 256, 0, stream>>>(x, mean, offsets, deg, csr);
        sage_transform_kernel<<<N_NODES / 8, 512, 0, stream>>>(
            x, mean, Wl + (size_t)l * H * H, bl + (size_t)l * H, Wr + (size_t)l * H * H);
    }

    mlp_kernel<<<BATCH / 8, 256, 0, stream>>>(x, user_ids, item_ids, W1, b1, W2, b2, out);
}